// Round 10
// baseline (11.877 us; speedup 1.0000x reference)
//
#include <hip/hip_runtime.h>
#include <math.h>

#define H_OUT 225
#define W_OUT 400
#define NPIX (H_OUT * W_OUT)      // 90000
#define NBOX 128
#define TW 16
#define TH 16
#define TX 25                      // 400/16
#define TY 15                      // ceil(225/16)
#define NBLK (TX * TY)             // 375
#define BS  256                    // 4 waves, 1 pixel/thread (best shape, R2/R9)

// EPS64 = np.finfo(np.float64).eps
#define EPS64F 2.2204460492503131e-16f

__global__ __launch_bounds__(BS) void segloss_main(
    const float* __restrict__ boxes,   // (128,4) [u1,v1,u2,v2]
    const float* __restrict__ pred,    // (1,2,225,400)
    float4* __restrict__ part4)        // NBLK float4 partials {sfg,sbg,snp,0}
{
    // packed box params: x=bx, y=by, z=r|(col<<16), w=bitcast(2*sigma^2)
    __shared__ int4 sbox[NBOX];
    __shared__ int  scnt[2];           // survivors per 64-box wave segment

    const int t = threadIdx.x;
    const int tileX = blockIdx.x % TX;
    const int tileY = blockIdx.x / TX;

    const int x = tileX * TW + (t & (TW - 1));
    const int y = tileY * TH + (t >> 4);
    const bool valid = (x < W_OUT) && (y < H_OUT);
    const int i = valid ? (y * W_OUT + x) : 0;

    // ---- issue the boxes load FIRST: stage A depends only on it ----
    float4 bv = make_float4(0.f, 0.f, 0.f, 0.f);
    if (t < NBOX)
        bv = reinterpret_cast<const float4*>(boxes)[t];   // one 16B load

    // prefetch focal-loss inputs (not needed until after stage B)
    const float pa = pred[i];
    const float pb = pred[NPIX + i];

    // tile bbox in source (900x1600) coordinates; pixel p samples source 4*p
    const int x0s = tileX * TW * 4, x1s = x0s + (TW - 1) * 4;
    const int y0s = tileY * TH * 4, y1s = y0s + (TH - 1) * 4;

    // ---- Stage A: waves 0-1 cull their 64 boxes into per-wave LDS segments ----
    if (t < NBOX) {
        const float hw = fabsf((bv.x - bv.z) * 0.5f);
        const float hh = fabsf((bv.y - bv.w) * 0.5f);
        const int   r  = (int)fmaxf(hw, hh);          // trunc, positive
        const int   bx = (int)((bv.x + bv.z) * 0.5f); // trunc
        const int   by = (int)((bv.y + bv.w) * 0.5f);
        const int   col = (hw <= hh) ? 1 : 0;
        const float sigma = (float)(2 * r + 1) / 6.0f;
        const float two_s2 = 2.0f * sigma * sigma;
        const bool keep = (bx + r >= x0s) && (bx - r <= x1s) &&
                          (by + r >= y0s) && (by - r <= y1s);
        const unsigned long long m = __ballot(keep);   // wave-wide (64 lanes)
        const int w = t >> 6, lane = t & 63;
        if (keep) {
            const int off = __popcll(m & ((1ull << lane) - 1ull));
            sbox[(w << 6) + off] = make_int4(bx, by, r | (col << 16),
                                             __float_as_int(two_s2));
        }
        if (lane == 0) scnt[w] = __popcll(m);
    }
    __syncthreads();                  // single sync: segments + counts visible

    // ---- Stage B: branchless predicated evaluation (R9, proven) ----
    float sfg = 0.0f, sbg = 0.0f, snp = 0.0f;
    if (valid) {
        const int px = x * 4;
        const int py = y * 4;
        float acc = 0.0f;
        #pragma unroll
        for (int seg = 0; seg < 2; ++seg) {
            const int base = seg << 6;
            const int n = scnt[seg];
            for (int k = 0; k < n; ++k) {
                const int4 bvp = sbox[base + k];      // one ds_read_b128
                const int dx = px - bvp.x;
                const int dy = py - bvp.y;
                const int rr = bvp.z & 0xFFFF;
                const int cl = bvp.z >> 16;
                const int hl  = rr >> 1;              // r//2
                const int hh2 = (rr + 1) >> 1;        // ceil(r/2)
                const bool inside = (dx <= rr) & (dx >= -rr) & (dy <= rr) & (dy >= -rr);
                const bool band = cl ? ((dx < -hl) | (dx >= hh2))
                                     : ((dy < -hh2) | (dy >= hh2));
                const float d2 = (float)(dx * dx + dy * dy);
                const float g  = expf(-d2 / __int_as_float(bvp.w));  // identical arithmetic
                const bool ok = inside & !band & (g >= EPS64F);
                acc += ok ? g : 0.0f;                 // v_cndmask + v_add, no branch
            }
        }

        const float fgs = fminf(fmaxf(acc, 0.0f), 1.0f);
        const bool  fgb = fgs > 0.5f;
        const float bgm = fgb ? 0.0f : 1.0f;
        const float w   = fgb ? 13.0f : 1.0f;
        const int   tgt = (int)fgs;           // 1 only where saturated to exactly 1.0

        const float mx  = fmaxf(pa, pb);
        const float lse = mx + logf(expf(pa - mx) + expf(pb - mx));
        const float logpt = (tgt ? pb : pa) - lse;
        const float pt = expf(logpt);
        const float om = 1.0f - pt;
        const float loss = -0.25f * om * om * logpt * w;

        sfg = loss * fgs;
        sbg = loss * bgm;
        snp = fgs + bgm;
    }

    // block reduction: wave shuffle + cross-wave LDS (4 waves)
    for (int o = 32; o > 0; o >>= 1) {
        sfg += __shfl_down(sfg, o);
        sbg += __shfl_down(sbg, o);
        snp += __shfl_down(snp, o);
    }
    __shared__ float rfg[BS / 64], rbg[BS / 64], rnp[BS / 64];
    const int wave = t >> 6, lane = t & 63;
    if (lane == 0) { rfg[wave] = sfg; rbg[wave] = sbg; rnp[wave] = snp; }
    __syncthreads();
    if (t == 0) {
        float a1 = 0.f, a2 = 0.f, a3 = 0.f;
        for (int wv = 0; wv < BS / 64; ++wv) { a1 += rfg[wv]; a2 += rbg[wv]; a3 += rnp[wv]; }
        part4[blockIdx.x] = make_float4(a1, a2, a3, 0.0f);   // one dwordx4 store
    }
}

__global__ __launch_bounds__(64) void segloss_final(
    const float4* __restrict__ part4, float* __restrict__ out)
{
    // single wave: 6 independent 16B loads/thread, pure-shuffle reduce,
    // no LDS, no __syncthreads  (6*64 = 384 >= 375)
    const int t = threadIdx.x;
    float f1 = 0.0f, f2 = 0.0f, f3 = 0.0f;
    #pragma unroll
    for (int q = 0; q < 6; ++q) {
        const int b = t + (q << 6);
        if (b < NBLK) {
            const float4 v = part4[b];       // independent loads, all in flight
            f1 += v.x; f2 += v.y; f3 += v.z;
        }
    }
    for (int o = 32; o > 0; o >>= 1) {
        f1 += __shfl_down(f1, o);
        f2 += __shfl_down(f2, o);
        f3 += __shfl_down(f3, o);
    }
    if (t == 0) out[0] = (f1 + f2) / f3;     // (fg_loss + bg_loss), WEIGHT = 1
}

extern "C" void kernel_launch(void* const* d_in, const int* in_sizes, int n_in,
                              void* d_out, int out_size, void* d_ws, size_t ws_size,
                              hipStream_t stream) {
    const float* boxes = (const float*)d_in[0];   // gt_boxes2d (128,4)
    // d_in[1] = images (900,1600): only its shape is used by the reference
    const float* pred  = (const float*)d_in[2];   // fg_pred (1,2,225,400)
    float* out  = (float*)d_out;
    float4* part4 = (float4*)d_ws;                // NBLK float4 = 6000 B

    segloss_main<<<NBLK, BS, 0, stream>>>(boxes, pred, part4);
    segloss_final<<<1, 64, 0, stream>>>(part4, out);
}

// Round 11
// 10.954 us; speedup vs baseline: 1.0843x; 1.0843x over previous
//
#include <hip/hip_runtime.h>
#include <math.h>

#define H_OUT 225
#define W_OUT 400
#define NPIX (H_OUT * W_OUT)      // 90000
#define NBOX 128
#define TW 16
#define TH 16
#define TX 25                      // 400/16
#define TY 15                      // ceil(225/16)
#define NBLK (TX * TY)             // 375
#define BS  256                    // 4 waves, 1 pixel/thread (best shape, R2/R9)

// EPS64 = np.finfo(np.float64).eps
#define EPS64F 2.2204460492503131e-16f

__global__ __launch_bounds__(BS) void segloss_main(
    const float* __restrict__ boxes,   // (128,4) [u1,v1,u2,v2]
    const float* __restrict__ pred,    // (1,2,225,400)
    float4* __restrict__ part4)        // NBLK float4 partials {sfg,sbg,snp,0}
{
    // packed box params: x=bx, y=by, z=r|(col<<16), w=bitcast(2*sigma^2)
    __shared__ int4 sbox[NBOX];
    __shared__ int  scnt[2];           // survivors per 64-box wave segment

    const int t = threadIdx.x;
    const int tileX = blockIdx.x % TX;
    const int tileY = blockIdx.x / TX;

    const int x = tileX * TW + (t & (TW - 1));
    const int y = tileY * TH + (t >> 4);
    const bool valid = (x < W_OUT) && (y < H_OUT);
    const int i = valid ? (y * W_OUT + x) : 0;

    // prefetch focal-loss inputs so global latency overlaps the box work
    const float pa = pred[i];
    const float pb = pred[NPIX + i];

    // tile bbox in source (900x1600) coordinates; pixel p samples source 4*p
    const int x0s = tileX * TW * 4, x1s = x0s + (TW - 1) * 4;
    const int y0s = tileY * TH * 4, y1s = y0s + (TH - 1) * 4;

    // ---- Stage A: waves 0-1 cull their 64 boxes into per-wave LDS segments ----
    if (t < NBOX) {
        const float4 bv = reinterpret_cast<const float4*>(boxes)[t];  // one 16B load
        const float hw = fabsf((bv.x - bv.z) * 0.5f);
        const float hh = fabsf((bv.y - bv.w) * 0.5f);
        const int   r  = (int)fmaxf(hw, hh);          // trunc, positive
        const int   bx = (int)((bv.x + bv.z) * 0.5f); // trunc
        const int   by = (int)((bv.y + bv.w) * 0.5f);
        const int   col = (hw <= hh) ? 1 : 0;
        const float sigma = (float)(2 * r + 1) / 6.0f;
        const float two_s2 = 2.0f * sigma * sigma;
        const bool keep = (bx + r >= x0s) && (bx - r <= x1s) &&
                          (by + r >= y0s) && (by - r <= y1s);
        const unsigned long long m = __ballot(keep);   // wave-wide (64 lanes)
        const int w = t >> 6, lane = t & 63;
        if (keep) {
            const int off = __popcll(m & ((1ull << lane) - 1ull));
            sbox[(w << 6) + off] = make_int4(bx, by, r | (col << 16),
                                             __float_as_int(two_s2));
        }
        if (lane == 0) scnt[w] = __popcll(m);
    }
    __syncthreads();                  // single sync: segments + counts visible

    // ---- Stage B: branchless predicated evaluation (pipelines, no branch chains) ----
    float sfg = 0.0f, sbg = 0.0f, snp = 0.0f;
    if (valid) {
        const int px = x * 4;
        const int py = y * 4;
        float acc = 0.0f;
        #pragma unroll
        for (int seg = 0; seg < 2; ++seg) {
            const int base = seg << 6;
            const int n = scnt[seg];
            for (int k = 0; k < n; ++k) {
                const int4 bvp = sbox[base + k];      // one ds_read_b128
                const int dx = px - bvp.x;
                const int dy = py - bvp.y;
                const int rr = bvp.z & 0xFFFF;
                const int cl = bvp.z >> 16;
                const int hl  = rr >> 1;              // r//2
                const int hh2 = (rr + 1) >> 1;        // ceil(r/2)
                const bool inside = (dx <= rr) & (dx >= -rr) & (dy <= rr) & (dy >= -rr);
                const bool band = cl ? ((dx < -hl) | (dx >= hh2))
                                     : ((dy < -hh2) | (dy >= hh2));
                const float d2 = (float)(dx * dx + dy * dy);
                const float g  = expf(-d2 / __int_as_float(bvp.w));  // identical arithmetic
                const bool ok = inside & !band & (g >= EPS64F);
                acc += ok ? g : 0.0f;                 // v_cndmask + v_add, no branch
            }
        }

        const float fgs = fminf(fmaxf(acc, 0.0f), 1.0f);
        const bool  fgb = fgs > 0.5f;
        const float bgm = fgb ? 0.0f : 1.0f;
        const float w   = fgb ? 13.0f : 1.0f;
        const int   tgt = (int)fgs;           // 1 only where saturated to exactly 1.0

        const float mx  = fmaxf(pa, pb);
        const float lse = mx + logf(expf(pa - mx) + expf(pb - mx));
        const float logpt = (tgt ? pb : pa) - lse;
        const float pt = expf(logpt);
        const float om = 1.0f - pt;
        const float loss = -0.25f * om * om * logpt * w;

        sfg = loss * fgs;
        sbg = loss * bgm;
        snp = fgs + bgm;
    }

    // block reduction: wave shuffle + cross-wave LDS (4 waves)
    for (int o = 32; o > 0; o >>= 1) {
        sfg += __shfl_down(sfg, o);
        sbg += __shfl_down(sbg, o);
        snp += __shfl_down(snp, o);
    }
    __shared__ float rfg[BS / 64], rbg[BS / 64], rnp[BS / 64];
    const int wave = t >> 6, lane = t & 63;
    if (lane == 0) { rfg[wave] = sfg; rbg[wave] = sbg; rnp[wave] = snp; }
    __syncthreads();
    if (t == 0) {
        float a1 = 0.f, a2 = 0.f, a3 = 0.f;
        for (int wv = 0; wv < BS / 64; ++wv) { a1 += rfg[wv]; a2 += rbg[wv]; a3 += rnp[wv]; }
        part4[blockIdx.x] = make_float4(a1, a2, a3, 0.0f);   // one dwordx4 store
    }
}

__global__ __launch_bounds__(BS) void segloss_final(
    const float4* __restrict__ part4, float* __restrict__ out)
{
    const int t = threadIdx.x;
    // 375 entries: thread t takes t and t+256 — two independent 16B loads
    float f1 = 0.0f, f2 = 0.0f, f3 = 0.0f;
    if (t < NBLK) {
        const float4 v = part4[t];
        f1 = v.x; f2 = v.y; f3 = v.z;
    }
    if (t + BS < NBLK) {
        const float4 v = part4[t + BS];
        f1 += v.x; f2 += v.y; f3 += v.z;
    }
    for (int o = 32; o > 0; o >>= 1) {
        f1 += __shfl_down(f1, o);
        f2 += __shfl_down(f2, o);
        f3 += __shfl_down(f3, o);
    }
    __shared__ float r1[BS / 64], r2[BS / 64], r3[BS / 64];
    const int wave = t >> 6, lane = t & 63;
    if (lane == 0) { r1[wave] = f1; r2[wave] = f2; r3[wave] = f3; }
    __syncthreads();
    if (t == 0) {
        float a1 = 0.f, a2 = 0.f, a3 = 0.f;
        for (int wv = 0; wv < BS / 64; ++wv) { a1 += r1[wv]; a2 += r2[wv]; a3 += r3[wv]; }
        out[0] = (a1 + a2) / a3;     // (fg_loss + bg_loss), WEIGHT = 1
    }
}

extern "C" void kernel_launch(void* const* d_in, const int* in_sizes, int n_in,
                              void* d_out, int out_size, void* d_ws, size_t ws_size,
                              hipStream_t stream) {
    const float* boxes = (const float*)d_in[0];   // gt_boxes2d (128,4)
    // d_in[1] = images (900,1600): only its shape is used by the reference
    const float* pred  = (const float*)d_in[2];   // fg_pred (1,2,225,400)
    float* out  = (float*)d_out;
    float4* part4 = (float4*)d_ws;                // NBLK float4 = 6000 B

    segloss_main<<<NBLK, BS, 0, stream>>>(boxes, pred, part4);
    segloss_final<<<1, BS, 0, stream>>>(part4, out);
}